// Round 1
// baseline (617.620 us; speedup 1.0000x reference)
//
#include <hip/hip_runtime.h>
#include <math.h>

#define NH 12
#define HD 64
#define NSEQ 1024
#define DMODEL 768

// ---------------------------------------------------------------------------
// QKV GEMM: qkv[m][c] = sum_k x[m][k]*qkv_w[c][k] + qkv_b[c]
// scatter into Q/K/V laid out [B][H][N][hd]
// 64x64 block tile, 256 threads, 4x4 per thread, K-chunks of 16.
// ---------------------------------------------------------------------------
__global__ __launch_bounds__(256) void qkv_gemm_kernel(
    const float* __restrict__ x, const float* __restrict__ w,
    const float* __restrict__ bias,
    float* __restrict__ Q, float* __restrict__ K, float* __restrict__ V)
{
    __shared__ float As[16][64];
    __shared__ float Bs[16][64];
    const int t = threadIdx.x;
    const int tn = t & 15, tm = t >> 4;
    const int m0 = blockIdx.y * 64, c0 = blockIdx.x * 64;
    float acc[4][4] = {};
    const int mm = t >> 2, kk = (t & 3) << 2;
    const float* xp = x + (size_t)(m0 + mm) * DMODEL + kk;
    const float* wp = w + (size_t)(c0 + mm) * DMODEL + kk;

    for (int k0 = 0; k0 < DMODEL; k0 += 16) {
        float4 av = *(const float4*)(xp + k0);
        float4 bv = *(const float4*)(wp + k0);
        __syncthreads();
        As[kk+0][mm] = av.x; As[kk+1][mm] = av.y; As[kk+2][mm] = av.z; As[kk+3][mm] = av.w;
        Bs[kk+0][mm] = bv.x; Bs[kk+1][mm] = bv.y; Bs[kk+2][mm] = bv.z; Bs[kk+3][mm] = bv.w;
        __syncthreads();
        #pragma unroll
        for (int k = 0; k < 16; ++k) {
            const float4 a4 = *(const float4*)&As[k][tm << 2];
            const float4 b4 = *(const float4*)&Bs[k][tn << 2];
            const float ar[4] = {a4.x, a4.y, a4.z, a4.w};
            const float br[4] = {b4.x, b4.y, b4.z, b4.w};
            #pragma unroll
            for (int i = 0; i < 4; ++i)
                #pragma unroll
                for (int j = 0; j < 4; ++j)
                    acc[i][j] += ar[i] * br[j];
        }
    }

    // epilogue: c0 is a multiple of 64 so the whole tile maps to one (s,h)
    const int s = c0 / DMODEL;
    const int rem = c0 % DMODEL;
    const int h = rem >> 6;
    float* outp = (s == 0) ? Q : (s == 1 ? K : V);
    const int b = m0 >> 10;
    const float4 bv4 = *(const float4*)&bias[c0 + (tn << 2)];
    #pragma unroll
    for (int i = 0; i < 4; ++i) {
        const int m = m0 + (tm << 2) + i;
        const int n = m & (NSEQ - 1);
        float4 o;
        o.x = acc[i][0] + bv4.x; o.y = acc[i][1] + bv4.y;
        o.z = acc[i][2] + bv4.z; o.w = acc[i][3] + bv4.w;
        *(float4*)&outp[((size_t)(b * NH + h) * NSEQ + n) * HD + (tn << 2)] = o;
    }
}

// ---------------------------------------------------------------------------
// Fused attention: per (b,h,i-tile of 64 rows), flash-style over 16 j-tiles.
// S = (Q*scale)K^T + rel_bias + elev_bias ; online softmax ; O = P V.
// P round-trips through LDS aliased onto the K buffer (stride 68 rows).
// Output written to O[b][n][h*64+d]  ([B,N,D] layout for proj).
// ---------------------------------------------------------------------------
__global__ __launch_bounds__(256) void attn_kernel(
    const float* __restrict__ Q, const float* __restrict__ K,
    const float* __restrict__ V,
    const float* __restrict__ coords, const float* __restrict__ elev,
    const float* __restrict__ table, const float* __restrict__ alpha_p,
    float* __restrict__ O)
{
    __shared__ float Qs[64][68];    // [d][i], pre-scaled
    __shared__ float KPs[64][68];   // K as [d][j], then reused as P [i][j]
    __shared__ float Vs[64][64];    // [j][d]
    __shared__ float tab[1024];     // bias_table[:, h]
    __shared__ int   lut[257];      // bucket(rel) for rel in [-128,128]
    __shared__ int   cxi[64], cyi[64], cxj[64], cyj[64];
    __shared__ float ei[64], ej[64];

    const int t = threadIdx.x;
    const int tn = t & 15, tm = t >> 4;
    const int bid = blockIdx.x;
    const int it = bid & 15;
    const int bh = bid >> 4;
    const int h = bh % NH, b = bh / NH;
    const int i0 = it * 64;
    const float alpha = alpha_p[0];

    for (int i = t; i < 1024; i += 256) tab[i] = table[i * NH + h];

    for (int r = t; r < 257; r += 256) {
        const int rel = r - 128;          // rel = cx_i - cx_j
        const int n = -rel;
        const int u = (n < 0) ? 16 : 0;
        const int a = n < 0 ? -n : n;
        int v;
        if (a < 8) {
            v = a;
        } else {
            const double lv = log((double)a / 8.0) / log(16.0) * 8.0;
            int vi = (int)(lv + 1e-9);
            v = 8 + vi;
            if (v > 15) v = 15;
        }
        lut[r] = u + v;
    }

    if (t < 64) {
        const float2 c = *(const float2*)&coords[(size_t)(b * NSEQ + i0 + t) * 2];
        cxi[t] = (int)(c.x * 128.0f);
        cyi[t] = (int)(c.y * 128.0f);
        ei[t]  = elev[b * NSEQ + i0 + t];
    }

    // Q tile, transposed + scaled
    const float* Qg = Q + ((size_t)bh * NSEQ + i0) * HD;
    for (int e = t; e < 1024; e += 256) {
        const int row = e >> 4, d0 = (e & 15) << 2;
        const float4 qv = *(const float4*)(Qg + row * HD + d0);
        const float sc = 0.125f;
        Qs[d0+0][row] = qv.x * sc; Qs[d0+1][row] = qv.y * sc;
        Qs[d0+2][row] = qv.z * sc; Qs[d0+3][row] = qv.w * sc;
    }

    float m_r[4], l_r[4], o_acc[4][4];
    #pragma unroll
    for (int i = 0; i < 4; ++i) {
        m_r[i] = -1e30f; l_r[i] = 0.0f;
        o_acc[i][0] = o_acc[i][1] = o_acc[i][2] = o_acc[i][3] = 0.0f;
    }

    const float* Kg = K + (size_t)bh * NSEQ * HD;
    const float* Vg = V + (size_t)bh * NSEQ * HD;

    for (int jt = 0; jt < 16; ++jt) {
        const int j0 = jt * 64;
        __syncthreads();   // previous PV readers done before overwriting LDS
        for (int e = t; e < 1024; e += 256) {
            const int row = e >> 4, d0 = (e & 15) << 2;
            const float4 kv = *(const float4*)(Kg + (size_t)(j0 + row) * HD + d0);
            KPs[d0+0][row] = kv.x; KPs[d0+1][row] = kv.y;
            KPs[d0+2][row] = kv.z; KPs[d0+3][row] = kv.w;
            const float4 vv = *(const float4*)(Vg + (size_t)(j0 + row) * HD + d0);
            *(float4*)&Vs[row][d0] = vv;
        }
        if (t < 64) {
            const float2 c = *(const float2*)&coords[(size_t)(b * NSEQ + j0 + t) * 2];
            cxj[t] = (int)(c.x * 128.0f);
            cyj[t] = (int)(c.y * 128.0f);
            ej[t]  = elev[b * NSEQ + j0 + t];
        }
        __syncthreads();

        // S tile
        float s[4][4] = {};
        #pragma unroll 8
        for (int d = 0; d < 64; ++d) {
            const float4 a4 = *(const float4*)&Qs[d][tm << 2];
            const float4 b4 = *(const float4*)&KPs[d][tn << 2];
            const float ar[4] = {a4.x, a4.y, a4.z, a4.w};
            const float br[4] = {b4.x, b4.y, b4.z, b4.w};
            #pragma unroll
            for (int i = 0; i < 4; ++i)
                #pragma unroll
                for (int j = 0; j < 4; ++j)
                    s[i][j] += ar[i] * br[j];
        }
        __syncthreads();   // done reading K from KPs; safe to overwrite with P

        // biases + online softmax (row groups = 16 lanes sharing tm)
        #pragma unroll
        for (int i = 0; i < 4; ++i) {
            const int ri = (tm << 2) + i;
            const int cx_i = cxi[ri], cy_i = cyi[ri];
            const float e_i = ei[ri];
            float rmax = -1e30f;
            #pragma unroll
            for (int jj = 0; jj < 4; ++jj) {
                const int jc = (tn << 2) + jj;
                const int bx = lut[cx_i - cxj[jc] + 128];
                const int by = lut[cy_i - cyj[jc] + 128];
                const float rb = tab[(bx << 5) + by];
                const float ed = (ej[jc] - e_i) * 1e-3f;
                const float eb = fmaxf(-alpha * fmaxf(ed, 0.0f), -10.0f);
                const float sv = s[i][jj] + rb + eb;
                s[i][jj] = sv;
                rmax = fmaxf(rmax, sv);
            }
            #pragma unroll
            for (int off = 1; off < 16; off <<= 1)
                rmax = fmaxf(rmax, __shfl_xor(rmax, off));
            const float m_new = fmaxf(m_r[i], rmax);
            const float corr = __expf(m_r[i] - m_new);
            m_r[i] = m_new;
            float rsum = 0.0f;
            #pragma unroll
            for (int jj = 0; jj < 4; ++jj) {
                const float pv = __expf(s[i][jj] - m_new);
                s[i][jj] = pv;
                rsum += pv;
            }
            #pragma unroll
            for (int off = 1; off < 16; off <<= 1)
                rsum += __shfl_xor(rsum, off);
            l_r[i] = l_r[i] * corr + rsum;
            o_acc[i][0] *= corr; o_acc[i][1] *= corr;
            o_acc[i][2] *= corr; o_acc[i][3] *= corr;
            *(float4*)&KPs[ri][tn << 2] = make_float4(s[i][0], s[i][1], s[i][2], s[i][3]);
        }
        __syncthreads();   // P fully written

        // O += P @ V
        #pragma unroll 8
        for (int j = 0; j < 64; ++j) {
            const float a0 = KPs[(tm << 2) + 0][j];
            const float a1 = KPs[(tm << 2) + 1][j];
            const float a2 = KPs[(tm << 2) + 2][j];
            const float a3 = KPs[(tm << 2) + 3][j];
            const float4 vv = *(const float4*)&Vs[j][tn << 2];
            o_acc[0][0] += a0 * vv.x; o_acc[0][1] += a0 * vv.y;
            o_acc[0][2] += a0 * vv.z; o_acc[0][3] += a0 * vv.w;
            o_acc[1][0] += a1 * vv.x; o_acc[1][1] += a1 * vv.y;
            o_acc[1][2] += a1 * vv.z; o_acc[1][3] += a1 * vv.w;
            o_acc[2][0] += a2 * vv.x; o_acc[2][1] += a2 * vv.y;
            o_acc[2][2] += a2 * vv.z; o_acc[2][3] += a2 * vv.w;
            o_acc[3][0] += a3 * vv.x; o_acc[3][1] += a3 * vv.y;
            o_acc[3][2] += a3 * vv.z; o_acc[3][3] += a3 * vv.w;
        }
    }

    float* Op = O + (size_t)(b * NSEQ + i0) * DMODEL + h * HD;
    #pragma unroll
    for (int i = 0; i < 4; ++i) {
        const float inv = 1.0f / l_r[i];
        const int ri = (tm << 2) + i;
        float4 o;
        o.x = o_acc[i][0] * inv; o.y = o_acc[i][1] * inv;
        o.z = o_acc[i][2] * inv; o.w = o_acc[i][3] * inv;
        *(float4*)&Op[(size_t)ri * DMODEL + (tn << 2)] = o;
    }
}

// ---------------------------------------------------------------------------
// Output projection: out[m][c] = sum_k O[m][k]*proj_w[c][k] + proj_b[c]
// ---------------------------------------------------------------------------
__global__ __launch_bounds__(256) void proj_gemm_kernel(
    const float* __restrict__ A, const float* __restrict__ w,
    const float* __restrict__ bias, float* __restrict__ out)
{
    __shared__ float As[16][64];
    __shared__ float Bs[16][64];
    const int t = threadIdx.x;
    const int tn = t & 15, tm = t >> 4;
    const int m0 = blockIdx.y * 64, c0 = blockIdx.x * 64;
    float acc[4][4] = {};
    const int mm = t >> 2, kk = (t & 3) << 2;
    const float* ap = A + (size_t)(m0 + mm) * DMODEL + kk;
    const float* wp = w + (size_t)(c0 + mm) * DMODEL + kk;

    for (int k0 = 0; k0 < DMODEL; k0 += 16) {
        float4 av = *(const float4*)(ap + k0);
        float4 bv = *(const float4*)(wp + k0);
        __syncthreads();
        As[kk+0][mm] = av.x; As[kk+1][mm] = av.y; As[kk+2][mm] = av.z; As[kk+3][mm] = av.w;
        Bs[kk+0][mm] = bv.x; Bs[kk+1][mm] = bv.y; Bs[kk+2][mm] = bv.z; Bs[kk+3][mm] = bv.w;
        __syncthreads();
        #pragma unroll
        for (int k = 0; k < 16; ++k) {
            const float4 a4 = *(const float4*)&As[k][tm << 2];
            const float4 b4 = *(const float4*)&Bs[k][tn << 2];
            const float ar[4] = {a4.x, a4.y, a4.z, a4.w};
            const float br[4] = {b4.x, b4.y, b4.z, b4.w};
            #pragma unroll
            for (int i = 0; i < 4; ++i)
                #pragma unroll
                for (int j = 0; j < 4; ++j)
                    acc[i][j] += ar[i] * br[j];
        }
    }

    const float4 bv4 = *(const float4*)&bias[c0 + (tn << 2)];
    #pragma unroll
    for (int i = 0; i < 4; ++i) {
        const int m = m0 + (tm << 2) + i;
        float4 o;
        o.x = acc[i][0] + bv4.x; o.y = acc[i][1] + bv4.y;
        o.z = acc[i][2] + bv4.z; o.w = acc[i][3] + bv4.w;
        *(float4*)&out[(size_t)m * DMODEL + c0 + (tn << 2)] = o;
    }
}

extern "C" void kernel_launch(void* const* d_in, const int* in_sizes, int n_in,
                              void* d_out, int out_size, void* d_ws, size_t ws_size,
                              hipStream_t stream) {
    const float* x       = (const float*)d_in[0];
    const float* coords  = (const float*)d_in[1];
    const float* elev    = (const float*)d_in[2];
    const float* qkv_w   = (const float*)d_in[3];
    const float* qkv_b   = (const float*)d_in[4];
    const float* proj_w  = (const float*)d_in[5];
    const float* proj_b  = (const float*)d_in[6];
    const float* btable  = (const float*)d_in[7];
    const float* alpha   = (const float*)d_in[8];
    float* out = (float*)d_out;

    const size_t per = (size_t)4 * NH * NSEQ * HD;   // 3,145,728 floats
    float* Q = (float*)d_ws;
    float* K = Q + per;
    float* V = K + per;
    float* O = V + per;

    qkv_gemm_kernel<<<dim3(36, 64), 256, 0, stream>>>(x, qkv_w, qkv_b, Q, K, V);
    attn_kernel<<<dim3(768), 256, 0, stream>>>(Q, K, V, coords, elev, btable, alpha, O);
    proj_gemm_kernel<<<dim3(12, 64), 256, 0, stream>>>(O, proj_w, proj_b, out);
}

// Round 2
// 229.903 us; speedup vs baseline: 2.6864x; 2.6864x over previous
//
#include <hip/hip_runtime.h>
#include <math.h>

#define NH 12
#define HD 64
#define NSEQ 1024
#define DMODEL 768

typedef unsigned short ushort_t;
typedef float f32x4 __attribute__((ext_vector_type(4)));
typedef short bf16x8 __attribute__((ext_vector_type(8)));

__device__ __forceinline__ ushort_t f2bf(float f) {
    unsigned int u = __float_as_uint(f);
    u += 0x7FFFu + ((u >> 16) & 1u);   // RNE
    return (ushort_t)(u >> 16);
}

// ---------------------------------------------------------------------------
// fp32 -> bf16 conversion of x, qkv_w, proj_w into contiguous ws region
// ---------------------------------------------------------------------------
#define XB_N   3145728u
#define WQB_N  1769472u
#define PWB_N  589824u

__global__ __launch_bounds__(256) void convert_kernel(
    const float* __restrict__ x, const float* __restrict__ w1,
    const float* __restrict__ w2, ushort_t* __restrict__ dst)
{
    const unsigned i = blockIdx.x * 256 + threadIdx.x;      // 8-elem chunk id
    const unsigned n0 = XB_N / 8, n1 = n0 + WQB_N / 8, n2 = n1 + PWB_N / 8;
    if (i >= n2) return;
    const float* src; unsigned off;
    if (i < n0)      { src = x;  off = i; }
    else if (i < n1) { src = w1; off = i - n0; }
    else             { src = w2; off = i - n1; }
    const float4 a = ((const float4*)src)[off * 2];
    const float4 b = ((const float4*)src)[off * 2 + 1];
    union { ushort_t u[8]; uint4 v; } pk;
    pk.u[0] = f2bf(a.x); pk.u[1] = f2bf(a.y); pk.u[2] = f2bf(a.z); pk.u[3] = f2bf(a.w);
    pk.u[4] = f2bf(b.x); pk.u[5] = f2bf(b.y); pk.u[6] = f2bf(b.z); pk.u[7] = f2bf(b.w);
    ((uint4*)dst)[i] = pk.v;
}

// ---------------------------------------------------------------------------
// QKV GEMM (bf16 MFMA): C[m][c] = sum_k xb[m][k]*wb[c][k] + bias[c]
// 128x128 tile, 256 thr (4 waves 2x2), BK=32, 16x16x32 MFMA.
// Epilogue scatters: Q (pre-scaled 1/8) and K as [bh][n][64] bf16,
// V transposed as [bh][d][n] bf16 (ushort4-packed over 4 consecutive n).
// ---------------------------------------------------------------------------
__global__ __launch_bounds__(256) void qkv_gemm(
    const ushort_t* __restrict__ A, const ushort_t* __restrict__ B,
    const float* __restrict__ bias,
    ushort_t* __restrict__ Qb, ushort_t* __restrict__ Kb, ushort_t* __restrict__ Vtb)
{
    __shared__ __align__(16) ushort_t As[128 * 40];
    __shared__ __align__(16) ushort_t Bs[128 * 40];
    const int t = threadIdx.x;
    const int lane = t & 63, w = t >> 6;
    const int wr = w >> 1, wc = w & 1;
    const int col = lane & 15, quad = lane >> 4;
    const int m0 = blockIdx.y * 128, c0 = blockIdx.x * 128;

    const f32x4 zero = {0.f, 0.f, 0.f, 0.f};
    f32x4 acc[4][4];
    #pragma unroll
    for (int i = 0; i < 4; ++i)
        #pragma unroll
        for (int j = 0; j < 4; ++j) acc[i][j] = zero;

    const int row_s = t >> 2, cq = (t & 3) * 8;     // staging coords (round 0)
    for (int k0 = 0; k0 < DMODEL; k0 += 32) {
        const uint4 a0 = *(const uint4*)&A[(size_t)(m0 + row_s) * DMODEL + k0 + cq];
        const uint4 a1 = *(const uint4*)&A[(size_t)(m0 + 64 + row_s) * DMODEL + k0 + cq];
        const uint4 b0 = *(const uint4*)&B[(size_t)(c0 + row_s) * DMODEL + k0 + cq];
        const uint4 b1 = *(const uint4*)&B[(size_t)(c0 + 64 + row_s) * DMODEL + k0 + cq];
        __syncthreads();
        *(uint4*)&As[row_s * 40 + cq] = a0;
        *(uint4*)&As[(64 + row_s) * 40 + cq] = a1;
        *(uint4*)&Bs[row_s * 40 + cq] = b0;
        *(uint4*)&Bs[(64 + row_s) * 40 + cq] = b1;
        __syncthreads();
        bf16x8 af[4], bf[4];
        #pragma unroll
        for (int im = 0; im < 4; ++im)
            af[im] = *(const bf16x8*)&As[(wr * 64 + im * 16 + col) * 40 + quad * 8];
        #pragma unroll
        for (int jn = 0; jn < 4; ++jn)
            bf[jn] = *(const bf16x8*)&Bs[(wc * 64 + jn * 16 + col) * 40 + quad * 8];
        #pragma unroll
        for (int im = 0; im < 4; ++im)
            #pragma unroll
            for (int jn = 0; jn < 4; ++jn)
                acc[im][jn] = __builtin_amdgcn_mfma_f32_16x16x32_bf16(af[im], bf[jn], acc[im][jn], 0, 0, 0);
    }

    // epilogue: wave's 64-col group maps to exactly one (s, h)
    const int cb = c0 + wc * 64;
    const int s = cb / DMODEL;
    const int h = (cb % DMODEL) >> 6;
    const int b = m0 >> 10;
    const int bh = b * NH + h;
    const int n0 = (m0 & (NSEQ - 1)) + wr * 64;

    #pragma unroll
    for (int im = 0; im < 4; ++im) {
        #pragma unroll
        for (int jn = 0; jn < 4; ++jn) {
            const int d = jn * 16 + col;
            const float bv = bias[cb + d];
            const f32x4 a = acc[im][jn];
            if (s == 0) {
                #pragma unroll
                for (int r = 0; r < 4; ++r) {
                    const int n = n0 + im * 16 + quad * 4 + r;
                    Qb[((size_t)bh * NSEQ + n) * HD + d] = f2bf((a[r] + bv) * 0.125f);
                }
            } else if (s == 1) {
                #pragma unroll
                for (int r = 0; r < 4; ++r) {
                    const int n = n0 + im * 16 + quad * 4 + r;
                    Kb[((size_t)bh * NSEQ + n) * HD + d] = f2bf(a[r] + bv);
                }
            } else {
                ushort4 p;
                p.x = f2bf(a[0] + bv); p.y = f2bf(a[1] + bv);
                p.z = f2bf(a[2] + bv); p.w = f2bf(a[3] + bv);
                *(ushort4*)&Vtb[((size_t)bh * HD + d) * NSEQ + n0 + im * 16 + quad * 4] = p;
            }
        }
    }
}

// ---------------------------------------------------------------------------
// Fused flash attention with bf16 MFMA.
// Block = 256 thr (4 waves), handles one (b,h,i-tile of 64 rows).
// Wave w owns S/O rows 16w..16w+15. P round-trips through LDS (wave-private rows).
// ---------------------------------------------------------------------------
__global__ __launch_bounds__(256) void attn_mfma(
    const ushort_t* __restrict__ Qb, const ushort_t* __restrict__ Kb,
    const ushort_t* __restrict__ Vtb,
    const float* __restrict__ coords, const float* __restrict__ elev,
    const float* __restrict__ table, const float* __restrict__ alpha_p,
    ushort_t* __restrict__ Ob)
{
    __shared__ __align__(16) ushort_t Qs[64 * 72];
    __shared__ __align__(16) ushort_t Ks[64 * 72];
    __shared__ __align__(16) ushort_t Vt[64 * 72];
    __shared__ __align__(16) ushort_t Ps[64 * 72];
    __shared__ float tab[1024];
    __shared__ int   lut[257];
    __shared__ int   cxi_s[64], cyi_s[64], cxj_s[64], cyj_s[64];
    __shared__ float ei_s[64], ej_s[64];

    const int t = threadIdx.x;
    const int lane = t & 63, w = t >> 6;
    const int col = lane & 15, quad = lane >> 4;
    const int bid = blockIdx.x;
    const int it = bid & 15, bh = bid >> 4;
    const int h = bh % NH, b = bh / NH;
    const int i0 = it * 64;
    const float alpha = alpha_p[0];

    for (int i = t; i < 1024; i += 256) tab[i] = table[i * NH + h];

    for (int r = t; r < 257; r += 256) {
        const int rel = r - 128;
        const int n = -rel;
        const int u = (n < 0) ? 16 : 0;
        const int a = n < 0 ? -n : n;
        int v;
        if (a < 8) v = a;
        else {
            const double lv = log((double)a / 8.0) / log(16.0) * 8.0;
            v = 8 + (int)(lv + 1e-9);
            if (v > 15) v = 15;
        }
        lut[r] = u + v;
    }

    if (t < 64) {
        const float2 c = *(const float2*)&coords[(size_t)(b * NSEQ + i0 + t) * 2];
        cxi_s[t] = (int)(c.x * 128.0f);
        cyi_s[t] = (int)(c.y * 128.0f);
        ei_s[t]  = elev[b * NSEQ + i0 + t];
    }

    // stage Q tile [64][64] -> Qs (padded 72)
    #pragma unroll
    for (int r2 = 0; r2 < 2; ++r2) {
        const int idx = r2 * 256 + t;
        const int row = idx >> 3, c8 = (idx & 7) * 8;
        *(uint4*)&Qs[row * 72 + c8] =
            *(const uint4*)&Qb[((size_t)bh * NSEQ + i0 + row) * HD + c8];
    }
    __syncthreads();

    bf16x8 aq0 = *(const bf16x8*)&Qs[(w * 16 + col) * 72 + quad * 8];
    bf16x8 aq1 = *(const bf16x8*)&Qs[(w * 16 + col) * 72 + 32 + quad * 8];

    const f32x4 zero = {0.f, 0.f, 0.f, 0.f};
    f32x4 o_acc[4];
    #pragma unroll
    for (int i = 0; i < 4; ++i) o_acc[i] = zero;
    float m_r[4] = {-1e30f, -1e30f, -1e30f, -1e30f};
    float l_r[4] = {0.f, 0.f, 0.f, 0.f};

    const size_t kvbase = (size_t)bh * NSEQ * HD;
    const int rowb = w * 16 + quad * 4;

    for (int jt = 0; jt < 16; ++jt) {
        const int j0 = jt * 64;
        __syncthreads();   // prior readers of Ks/Vt done
        #pragma unroll
        for (int r2 = 0; r2 < 2; ++r2) {
            const int idx = r2 * 256 + t;
            const int row = idx >> 3, c8 = (idx & 7) * 8;
            *(uint4*)&Ks[row * 72 + c8] =
                *(const uint4*)&Kb[kvbase + (size_t)(j0 + row) * HD + c8];
            *(uint4*)&Vt[row * 72 + c8] =
                *(const uint4*)&Vtb[kvbase + (size_t)row * NSEQ + j0 + c8];
        }
        if (t < 64) {
            const float2 c = *(const float2*)&coords[(size_t)(b * NSEQ + j0 + t) * 2];
            cxj_s[t] = (int)(c.x * 128.0f);
            cyj_s[t] = (int)(c.y * 128.0f);
            ej_s[t]  = elev[b * NSEQ + j0 + t];
        }
        __syncthreads();

        // S = Q K^T  (4 col-blocks x 2 k-chunks)
        f32x4 sacc[4];
        #pragma unroll
        for (int jb = 0; jb < 4; ++jb) {
            sacc[jb] = zero;
            const bf16x8 b0 = *(const bf16x8*)&Ks[(jb * 16 + col) * 72 + quad * 8];
            const bf16x8 b1 = *(const bf16x8*)&Ks[(jb * 16 + col) * 72 + 32 + quad * 8];
            sacc[jb] = __builtin_amdgcn_mfma_f32_16x16x32_bf16(aq0, b0, sacc[jb], 0, 0, 0);
            sacc[jb] = __builtin_amdgcn_mfma_f32_16x16x32_bf16(aq1, b1, sacc[jb], 0, 0, 0);
        }

        // biases + online softmax in C-layout; write P (bf16) to LDS
        #pragma unroll
        for (int r = 0; r < 4; ++r) {
            const int ri = rowb + r;
            const int cx_i = cxi_s[ri], cy_i = cyi_s[ri];
            const float e_i = ei_s[ri];
            float sv[4];
            float rmax = -1e30f;
            #pragma unroll
            for (int jb = 0; jb < 4; ++jb) {
                const int jl = jb * 16 + col;
                const int bx = lut[cx_i - cxj_s[jl] + 128];
                const int by = lut[cy_i - cyj_s[jl] + 128];
                const float rb = tab[(bx << 5) + by];
                const float ed = (ej_s[jl] - e_i) * 1e-3f;
                const float eb = fminf(fmaxf(-alpha * fmaxf(ed, 0.f), -10.f), 0.f);
                sv[jb] = sacc[jb][r] + rb + eb;
                rmax = fmaxf(rmax, sv[jb]);
            }
            #pragma unroll
            for (int off = 1; off < 16; off <<= 1)
                rmax = fmaxf(rmax, __shfl_xor(rmax, off));
            const float m_new = fmaxf(m_r[r], rmax);
            const float corr = __expf(m_r[r] - m_new);
            m_r[r] = m_new;
            float rsum = 0.f;
            #pragma unroll
            for (int jb = 0; jb < 4; ++jb) {
                const float p = __expf(sv[jb] - m_new);
                rsum += p;
                Ps[ri * 72 + jb * 16 + col] = f2bf(p);
            }
            #pragma unroll
            for (int off = 1; off < 16; off <<= 1)
                rsum += __shfl_xor(rsum, off);
            l_r[r] = l_r[r] * corr + rsum;
            #pragma unroll
            for (int db = 0; db < 4; ++db) o_acc[db][r] *= corr;
        }
        __syncthreads();   // P visible (cross-lane within wave via LDS)

        // O += P V
        const bf16x8 ap0 = *(const bf16x8*)&Ps[(w * 16 + col) * 72 + quad * 8];
        const bf16x8 ap1 = *(const bf16x8*)&Ps[(w * 16 + col) * 72 + 32 + quad * 8];
        #pragma unroll
        for (int db = 0; db < 4; ++db) {
            const bf16x8 v0 = *(const bf16x8*)&Vt[(db * 16 + col) * 72 + quad * 8];
            const bf16x8 v1 = *(const bf16x8*)&Vt[(db * 16 + col) * 72 + 32 + quad * 8];
            o_acc[db] = __builtin_amdgcn_mfma_f32_16x16x32_bf16(ap0, v0, o_acc[db], 0, 0, 0);
            o_acc[db] = __builtin_amdgcn_mfma_f32_16x16x32_bf16(ap1, v1, o_acc[db], 0, 0, 0);
        }
    }

    // write O (bf16) in [B*N][768] layout for proj
    #pragma unroll
    for (int r = 0; r < 4; ++r) {
        const float inv = 1.f / l_r[r];
        const int ri = rowb + r;
        const size_t base = ((size_t)(b * NSEQ) + i0 + ri) * DMODEL + h * HD;
        #pragma unroll
        for (int db = 0; db < 4; ++db)
            Ob[base + db * 16 + col] = f2bf(o_acc[db][r] * inv);
    }
}

// ---------------------------------------------------------------------------
// Proj GEMM (bf16 MFMA): out[m][c] = sum_k Ob[m][k]*pwb[c][k] + pb[c]  (fp32 out)
// ---------------------------------------------------------------------------
__global__ __launch_bounds__(256) void proj_gemm(
    const ushort_t* __restrict__ A, const ushort_t* __restrict__ B,
    const float* __restrict__ bias, float* __restrict__ out)
{
    __shared__ __align__(16) ushort_t As[128 * 40];
    __shared__ __align__(16) ushort_t Bs[128 * 40];
    const int t = threadIdx.x;
    const int lane = t & 63, w = t >> 6;
    const int wr = w >> 1, wc = w & 1;
    const int col = lane & 15, quad = lane >> 4;
    const int m0 = blockIdx.y * 128, c0 = blockIdx.x * 128;

    const f32x4 zero = {0.f, 0.f, 0.f, 0.f};
    f32x4 acc[4][4];
    #pragma unroll
    for (int i = 0; i < 4; ++i)
        #pragma unroll
        for (int j = 0; j < 4; ++j) acc[i][j] = zero;

    const int row_s = t >> 2, cq = (t & 3) * 8;
    for (int k0 = 0; k0 < DMODEL; k0 += 32) {
        const uint4 a0 = *(const uint4*)&A[(size_t)(m0 + row_s) * DMODEL + k0 + cq];
        const uint4 a1 = *(const uint4*)&A[(size_t)(m0 + 64 + row_s) * DMODEL + k0 + cq];
        const uint4 b0 = *(const uint4*)&B[(size_t)(c0 + row_s) * DMODEL + k0 + cq];
        const uint4 b1 = *(const uint4*)&B[(size_t)(c0 + 64 + row_s) * DMODEL + k0 + cq];
        __syncthreads();
        *(uint4*)&As[row_s * 40 + cq] = a0;
        *(uint4*)&As[(64 + row_s) * 40 + cq] = a1;
        *(uint4*)&Bs[row_s * 40 + cq] = b0;
        *(uint4*)&Bs[(64 + row_s) * 40 + cq] = b1;
        __syncthreads();
        bf16x8 af[4], bf[4];
        #pragma unroll
        for (int im = 0; im < 4; ++im)
            af[im] = *(const bf16x8*)&As[(wr * 64 + im * 16 + col) * 40 + quad * 8];
        #pragma unroll
        for (int jn = 0; jn < 4; ++jn)
            bf[jn] = *(const bf16x8*)&Bs[(wc * 64 + jn * 16 + col) * 40 + quad * 8];
        #pragma unroll
        for (int im = 0; im < 4; ++im)
            #pragma unroll
            for (int jn = 0; jn < 4; ++jn)
                acc[im][jn] = __builtin_amdgcn_mfma_f32_16x16x32_bf16(af[im], bf[jn], acc[im][jn], 0, 0, 0);
    }

    #pragma unroll
    for (int im = 0; im < 4; ++im) {
        #pragma unroll
        for (int jn = 0; jn < 4; ++jn) {
            const int c = c0 + wc * 64 + jn * 16 + col;
            const float bv = bias[c];
            #pragma unroll
            for (int r = 0; r < 4; ++r) {
                const int m = m0 + wr * 64 + im * 16 + quad * 4 + r;
                out[(size_t)m * DMODEL + c] = acc[im][jn][r] + bv;
            }
        }
    }
}

extern "C" void kernel_launch(void* const* d_in, const int* in_sizes, int n_in,
                              void* d_out, int out_size, void* d_ws, size_t ws_size,
                              hipStream_t stream) {
    const float* x       = (const float*)d_in[0];
    const float* coords  = (const float*)d_in[1];
    const float* elev    = (const float*)d_in[2];
    const float* qkv_w   = (const float*)d_in[3];
    const float* qkv_b   = (const float*)d_in[4];
    const float* proj_w  = (const float*)d_in[5];
    const float* proj_b  = (const float*)d_in[6];
    const float* btable  = (const float*)d_in[7];
    const float* alpha   = (const float*)d_in[8];
    float* out = (float*)d_out;

    ushort_t* wsu = (ushort_t*)d_ws;
    ushort_t* xb  = wsu;
    ushort_t* wqb = wsu + 3145728;
    ushort_t* pwb = wsu + 4915200;
    ushort_t* Qb  = wsu + 5505024;
    ushort_t* Kb  = wsu + 8650752;
    ushort_t* Vtb = wsu + 11796480;
    ushort_t* Ob  = wsu + 14942208;

    convert_kernel<<<2688, 256, 0, stream>>>(x, qkv_w, proj_w, wsu);
    qkv_gemm<<<dim3(18, 32), 256, 0, stream>>>(xb, wqb, qkv_b, Qb, Kb, Vtb);
    attn_mfma<<<768, 256, 0, stream>>>(Qb, Kb, Vtb, coords, elev, btable, alpha, Ob);
    proj_gemm<<<dim3(6, 32), 256, 0, stream>>>(Ob, pwb, proj_b, out);
}

// Round 3
// 219.604 us; speedup vs baseline: 2.8124x; 1.0469x over previous
//
#include <hip/hip_runtime.h>
#include <math.h>

#define NH 12
#define HD 64
#define NSEQ 1024
#define DMODEL 768

typedef unsigned short ushort_t;
typedef float f32x4 __attribute__((ext_vector_type(4)));
typedef short bf16x8 __attribute__((ext_vector_type(8)));

__device__ __forceinline__ ushort_t f2bf(float f) {
    unsigned int u = __float_as_uint(f);
    u += 0x7FFFu + ((u >> 16) & 1u);   // RNE
    return (ushort_t)(u >> 16);
}

// ---------------------------------------------------------------------------
// fp32 -> bf16 conversion of x, qkv_w, proj_w into contiguous ws region
// ---------------------------------------------------------------------------
#define XB_N   3145728u
#define WQB_N  1769472u
#define PWB_N  589824u

__global__ __launch_bounds__(256) void convert_kernel(
    const float* __restrict__ x, const float* __restrict__ w1,
    const float* __restrict__ w2, ushort_t* __restrict__ dst)
{
    const unsigned i = blockIdx.x * 256 + threadIdx.x;      // 8-elem chunk id
    const unsigned n0 = XB_N / 8, n1 = n0 + WQB_N / 8, n2 = n1 + PWB_N / 8;
    if (i >= n2) return;
    const float* src; unsigned off;
    if (i < n0)      { src = x;  off = i; }
    else if (i < n1) { src = w1; off = i - n0; }
    else             { src = w2; off = i - n1; }
    const float4 a = ((const float4*)src)[off * 2];
    const float4 b = ((const float4*)src)[off * 2 + 1];
    union { ushort_t u[8]; uint4 v; } pk;
    pk.u[0] = f2bf(a.x); pk.u[1] = f2bf(a.y); pk.u[2] = f2bf(a.z); pk.u[3] = f2bf(a.w);
    pk.u[4] = f2bf(b.x); pk.u[5] = f2bf(b.y); pk.u[6] = f2bf(b.z); pk.u[7] = f2bf(b.w);
    ((uint4*)dst)[i] = pk.v;
}

// ---------------------------------------------------------------------------
// bias_pre: per (b,i,j) pack = (bf16(elev_bias) << 16) | bucket_idx
// bucket via pure arithmetic (log2f); fractional gaps >= 0.015 so fp32 exact.
// ---------------------------------------------------------------------------
__device__ __forceinline__ int bucketf(int rel) {
    const int n = -rel;
    const int u = (n < 0) ? 16 : 0;
    const int a = n < 0 ? -n : n;
    if (a < 8) return u + a;
    int v = 8 + (int)(log2f((float)a * 0.125f) * 2.0f + 1e-4f);
    if (v > 15) v = 15;
    return u + v;
}

__global__ __launch_bounds__(256) void bias_pre(
    const float* __restrict__ coords, const float* __restrict__ elev,
    const float* __restrict__ alpha_p, unsigned* __restrict__ pack)
{
    const int blk = blockIdx.x;
    const int b = blk >> 10, i = blk & 1023;
    const int t = threadIdx.x;
    const float alpha = alpha_p[0];
    const float2 ci = *(const float2*)&coords[(size_t)(b * NSEQ + i) * 2];
    const int cxi = (int)(ci.x * 128.0f), cyi = (int)(ci.y * 128.0f);
    const float ei = elev[b * NSEQ + i];
    const int j0 = t * 4;
    const float4 c01 = *(const float4*)&coords[(size_t)(b * NSEQ + j0) * 2];
    const float4 c23 = *(const float4*)&coords[(size_t)(b * NSEQ + j0 + 2) * 2];
    const float4 ej4 = *(const float4*)&elev[b * NSEQ + j0];
    const float cjx[4] = {c01.x, c01.z, c23.x, c23.z};
    const float cjy[4] = {c01.y, c01.w, c23.y, c23.w};
    const float ejv[4] = {ej4.x, ej4.y, ej4.z, ej4.w};
    unsigned r[4];
    #pragma unroll
    for (int k = 0; k < 4; ++k) {
        const int bx = bucketf(cxi - (int)(cjx[k] * 128.0f));
        const int by = bucketf(cyi - (int)(cjy[k] * 128.0f));
        const int idx = (bx << 5) + by;
        const float ed = (ejv[k] - ei) * 1e-3f;
        const float eb = fmaxf(-alpha * fmaxf(ed, 0.0f), -10.0f);  // <= 0 always
        r[k] = ((unsigned)f2bf(eb) << 16) | (unsigned)idx;
    }
    uint4 o; o.x = r[0]; o.y = r[1]; o.z = r[2]; o.w = r[3];
    *(uint4*)&pack[((size_t)b << 20) + (size_t)i * NSEQ + j0] = o;
}

// ---------------------------------------------------------------------------
// QKV GEMM (bf16 MFMA): 128x128 tile, 256 thr, BK=32, 16x16x32 MFMA.
// ---------------------------------------------------------------------------
__global__ __launch_bounds__(256) void qkv_gemm(
    const ushort_t* __restrict__ A, const ushort_t* __restrict__ B,
    const float* __restrict__ bias,
    ushort_t* __restrict__ Qb, ushort_t* __restrict__ Kb, ushort_t* __restrict__ Vtb)
{
    __shared__ __align__(16) ushort_t As[128 * 40];
    __shared__ __align__(16) ushort_t Bs[128 * 40];
    const int t = threadIdx.x;
    const int lane = t & 63, w = t >> 6;
    const int wr = w >> 1, wc = w & 1;
    const int col = lane & 15, quad = lane >> 4;
    const int m0 = blockIdx.y * 128, c0 = blockIdx.x * 128;

    const f32x4 zero = {0.f, 0.f, 0.f, 0.f};
    f32x4 acc[4][4];
    #pragma unroll
    for (int i = 0; i < 4; ++i)
        #pragma unroll
        for (int j = 0; j < 4; ++j) acc[i][j] = zero;

    const int row_s = t >> 2, cq = (t & 3) * 8;
    for (int k0 = 0; k0 < DMODEL; k0 += 32) {
        const uint4 a0 = *(const uint4*)&A[(size_t)(m0 + row_s) * DMODEL + k0 + cq];
        const uint4 a1 = *(const uint4*)&A[(size_t)(m0 + 64 + row_s) * DMODEL + k0 + cq];
        const uint4 b0 = *(const uint4*)&B[(size_t)(c0 + row_s) * DMODEL + k0 + cq];
        const uint4 b1 = *(const uint4*)&B[(size_t)(c0 + 64 + row_s) * DMODEL + k0 + cq];
        __syncthreads();
        *(uint4*)&As[row_s * 40 + cq] = a0;
        *(uint4*)&As[(64 + row_s) * 40 + cq] = a1;
        *(uint4*)&Bs[row_s * 40 + cq] = b0;
        *(uint4*)&Bs[(64 + row_s) * 40 + cq] = b1;
        __syncthreads();
        bf16x8 af[4], bf[4];
        #pragma unroll
        for (int im = 0; im < 4; ++im)
            af[im] = *(const bf16x8*)&As[(wr * 64 + im * 16 + col) * 40 + quad * 8];
        #pragma unroll
        for (int jn = 0; jn < 4; ++jn)
            bf[jn] = *(const bf16x8*)&Bs[(wc * 64 + jn * 16 + col) * 40 + quad * 8];
        #pragma unroll
        for (int im = 0; im < 4; ++im)
            #pragma unroll
            for (int jn = 0; jn < 4; ++jn)
                acc[im][jn] = __builtin_amdgcn_mfma_f32_16x16x32_bf16(af[im], bf[jn], acc[im][jn], 0, 0, 0);
    }

    const int cb = c0 + wc * 64;
    const int s = cb / DMODEL;
    const int h = (cb % DMODEL) >> 6;
    const int b = m0 >> 10;
    const int bh = b * NH + h;
    const int n0 = (m0 & (NSEQ - 1)) + wr * 64;

    #pragma unroll
    for (int im = 0; im < 4; ++im) {
        #pragma unroll
        for (int jn = 0; jn < 4; ++jn) {
            const int d = jn * 16 + col;
            const float bv = bias[cb + d];
            const f32x4 a = acc[im][jn];
            if (s == 0) {
                #pragma unroll
                for (int r = 0; r < 4; ++r) {
                    const int n = n0 + im * 16 + quad * 4 + r;
                    Qb[((size_t)bh * NSEQ + n) * HD + d] = f2bf((a[r] + bv) * 0.125f);
                }
            } else if (s == 1) {
                #pragma unroll
                for (int r = 0; r < 4; ++r) {
                    const int n = n0 + im * 16 + quad * 4 + r;
                    Kb[((size_t)bh * NSEQ + n) * HD + d] = f2bf(a[r] + bv);
                }
            } else {
                ushort4 p;
                p.x = f2bf(a[0] + bv); p.y = f2bf(a[1] + bv);
                p.z = f2bf(a[2] + bv); p.w = f2bf(a[3] + bv);
                *(ushort4*)&Vtb[((size_t)bh * HD + d) * NSEQ + n0 + im * 16 + quad * 4] = p;
            }
        }
    }
}

// ---------------------------------------------------------------------------
// Fused flash attention with bf16 MFMA + precomputed packed bias.
// Block = 256 thr (4 waves) = one (b,h,i-tile of 64 rows).
// P aliases the Q staging buffer (Q lives in registers after frag load).
// ---------------------------------------------------------------------------
__global__ __launch_bounds__(256) void attn_mfma(
    const ushort_t* __restrict__ Qb, const ushort_t* __restrict__ Kb,
    const ushort_t* __restrict__ Vtb,
    const unsigned* __restrict__ pack,
    const float* __restrict__ table,
    ushort_t* __restrict__ Ob)
{
    __shared__ __align__(16) ushort_t QPs[64 * 72];   // Q staging, then P
    __shared__ __align__(16) ushort_t Ks[64 * 72];
    __shared__ __align__(16) ushort_t Vt[64 * 72];
    __shared__ float tab[1024];
    __shared__ float red[4];

    const int t = threadIdx.x;
    const int lane = t & 63, w = t >> 6;
    const int col = lane & 15, quad = lane >> 4;
    const int bid = blockIdx.x;
    const int it = bid & 15, bh = bid >> 4;
    const int h = bh % NH, b = bh / NH;
    const int i0 = it * 64;

    // load per-head table column + block max
    float lm = -1e30f;
    for (int i = t; i < 1024; i += 256) {
        const float v = table[i * NH + h];
        tab[i] = v;
        lm = fmaxf(lm, v);
    }
    #pragma unroll
    for (int off = 1; off < 64; off <<= 1)
        lm = fmaxf(lm, __shfl_xor(lm, off));
    if (lane == 0) red[w] = lm;

    // stage Q tile [64][64] -> QPs (stride 72)
    #pragma unroll
    for (int r2 = 0; r2 < 2; ++r2) {
        const int idx = r2 * 256 + t;
        const int row = idx >> 3, c8 = (idx & 7) * 8;
        *(uint4*)&QPs[row * 72 + c8] =
            *(const uint4*)&Qb[((size_t)bh * NSEQ + i0 + row) * HD + c8];
    }
    __syncthreads();

    const float maxrb = fmaxf(fmaxf(red[0], red[1]), fmaxf(red[2], red[3]));
    const bf16x8 aq0 = *(const bf16x8*)&QPs[(w * 16 + col) * 72 + quad * 8];
    const bf16x8 aq1 = *(const bf16x8*)&QPs[(w * 16 + col) * 72 + 32 + quad * 8];

    const f32x4 zero = {0.f, 0.f, 0.f, 0.f};
    f32x4 o_acc[4];
    #pragma unroll
    for (int i = 0; i < 4; ++i) o_acc[i] = zero;
    float m_r[4] = {-1e30f, -1e30f, -1e30f, -1e30f};
    float l_r[4] = {0.f, 0.f, 0.f, 0.f};

    const size_t kvbase = (size_t)bh * NSEQ * HD;
    const int rowb = w * 16 + quad * 4;
    const unsigned* prow = pack + ((size_t)b << 20) + (size_t)(i0 + rowb) * NSEQ + col;

    for (int jt = 0; jt < 16; ++jt) {
        const int j0 = jt * 64;
        __syncthreads();   // prior readers of Ks/Vt/QPs done
        #pragma unroll
        for (int r2 = 0; r2 < 2; ++r2) {
            const int idx = r2 * 256 + t;
            const int row = idx >> 3, c8 = (idx & 7) * 8;
            *(uint4*)&Ks[row * 72 + c8] =
                *(const uint4*)&Kb[kvbase + (size_t)(j0 + row) * HD + c8];
            *(uint4*)&Vt[row * 72 + c8] =
                *(const uint4*)&Vtb[kvbase + (size_t)row * NSEQ + j0 + c8];
        }

        // prefetch packed bias (latency hides under staging + MFMA)
        unsigned pk[4][4];
        #pragma unroll
        for (int r = 0; r < 4; ++r)
            #pragma unroll
            for (int jb = 0; jb < 4; ++jb)
                pk[r][jb] = prow[(size_t)r * NSEQ + j0 + jb * 16];
        __syncthreads();

        // S = Q K^T
        f32x4 sacc[4];
        #pragma unroll
        for (int jb = 0; jb < 4; ++jb) {
            sacc[jb] = zero;
            const bf16x8 b0 = *(const bf16x8*)&Ks[(jb * 16 + col) * 72 + quad * 8];
            const bf16x8 b1 = *(const bf16x8*)&Ks[(jb * 16 + col) * 72 + 32 + quad * 8];
            sacc[jb] = __builtin_amdgcn_mfma_f32_16x16x32_bf16(aq0, b0, sacc[jb], 0, 0, 0);
            sacc[jb] = __builtin_amdgcn_mfma_f32_16x16x32_bf16(aq1, b1, sacc[jb], 0, 0, 0);
        }

        // online softmax; m-hat = rowmax(S) + maxrb bounds the biased max
        #pragma unroll
        for (int r = 0; r < 4; ++r) {
            const int ri = rowb + r;
            float rmax = fmaxf(fmaxf(sacc[0][r], sacc[1][r]),
                               fmaxf(sacc[2][r], sacc[3][r]));
            #pragma unroll
            for (int off = 1; off < 16; off <<= 1)
                rmax = fmaxf(rmax, __shfl_xor(rmax, off));
            const float m_new = fmaxf(m_r[r], rmax + maxrb);
            const float corr = __expf(m_r[r] - m_new);
            m_r[r] = m_new;
            float rsum = 0.f;
            #pragma unroll
            for (int jb = 0; jb < 4; ++jb) {
                const unsigned pkv = pk[r][jb];
                const float ebf = __uint_as_float(pkv & 0xFFFF0000u);
                const float rb = tab[pkv & 1023u];
                const float p = __expf(sacc[jb][r] + rb + ebf - m_new);
                rsum += p;
                QPs[ri * 72 + jb * 16 + col] = f2bf(p);
            }
            #pragma unroll
            for (int off = 1; off < 16; off <<= 1)
                rsum += __shfl_xor(rsum, off);
            l_r[r] = l_r[r] * corr + rsum;
            #pragma unroll
            for (int db = 0; db < 4; ++db) o_acc[db][r] *= corr;
        }
        __syncthreads();   // P published

        // O += P V
        const bf16x8 ap0 = *(const bf16x8*)&QPs[(w * 16 + col) * 72 + quad * 8];
        const bf16x8 ap1 = *(const bf16x8*)&QPs[(w * 16 + col) * 72 + 32 + quad * 8];
        #pragma unroll
        for (int db = 0; db < 4; ++db) {
            const bf16x8 v0 = *(const bf16x8*)&Vt[(db * 16 + col) * 72 + quad * 8];
            const bf16x8 v1 = *(const bf16x8*)&Vt[(db * 16 + col) * 72 + 32 + quad * 8];
            o_acc[db] = __builtin_amdgcn_mfma_f32_16x16x32_bf16(ap0, v0, o_acc[db], 0, 0, 0);
            o_acc[db] = __builtin_amdgcn_mfma_f32_16x16x32_bf16(ap1, v1, o_acc[db], 0, 0, 0);
        }
    }

    #pragma unroll
    for (int r = 0; r < 4; ++r) {
        const float inv = 1.f / l_r[r];
        const int ri = rowb + r;
        const size_t base = ((size_t)(b * NSEQ) + i0 + ri) * DMODEL + h * HD;
        #pragma unroll
        for (int db = 0; db < 4; ++db)
            Ob[base + db * 16 + col] = f2bf(o_acc[db][r] * inv);
    }
}

// ---------------------------------------------------------------------------
// Proj GEMM (bf16 MFMA): fp32 out
// ---------------------------------------------------------------------------
__global__ __launch_bounds__(256) void proj_gemm(
    const ushort_t* __restrict__ A, const ushort_t* __restrict__ B,
    const float* __restrict__ bias, float* __restrict__ out)
{
    __shared__ __align__(16) ushort_t As[128 * 40];
    __shared__ __align__(16) ushort_t Bs[128 * 40];
    const int t = threadIdx.x;
    const int lane = t & 63, w = t >> 6;
    const int wr = w >> 1, wc = w & 1;
    const int col = lane & 15, quad = lane >> 4;
    const int m0 = blockIdx.y * 128, c0 = blockIdx.x * 128;

    const f32x4 zero = {0.f, 0.f, 0.f, 0.f};
    f32x4 acc[4][4];
    #pragma unroll
    for (int i = 0; i < 4; ++i)
        #pragma unroll
        for (int j = 0; j < 4; ++j) acc[i][j] = zero;

    const int row_s = t >> 2, cq = (t & 3) * 8;
    for (int k0 = 0; k0 < DMODEL; k0 += 32) {
        const uint4 a0 = *(const uint4*)&A[(size_t)(m0 + row_s) * DMODEL + k0 + cq];
        const uint4 a1 = *(const uint4*)&A[(size_t)(m0 + 64 + row_s) * DMODEL + k0 + cq];
        const uint4 b0 = *(const uint4*)&B[(size_t)(c0 + row_s) * DMODEL + k0 + cq];
        const uint4 b1 = *(const uint4*)&B[(size_t)(c0 + 64 + row_s) * DMODEL + k0 + cq];
        __syncthreads();
        *(uint4*)&As[row_s * 40 + cq] = a0;
        *(uint4*)&As[(64 + row_s) * 40 + cq] = a1;
        *(uint4*)&Bs[row_s * 40 + cq] = b0;
        *(uint4*)&Bs[(64 + row_s) * 40 + cq] = b1;
        __syncthreads();
        bf16x8 af[4], bf[4];
        #pragma unroll
        for (int im = 0; im < 4; ++im)
            af[im] = *(const bf16x8*)&As[(wr * 64 + im * 16 + col) * 40 + quad * 8];
        #pragma unroll
        for (int jn = 0; jn < 4; ++jn)
            bf[jn] = *(const bf16x8*)&Bs[(wc * 64 + jn * 16 + col) * 40 + quad * 8];
        #pragma unroll
        for (int im = 0; im < 4; ++im)
            #pragma unroll
            for (int jn = 0; jn < 4; ++jn)
                acc[im][jn] = __builtin_amdgcn_mfma_f32_16x16x32_bf16(af[im], bf[jn], acc[im][jn], 0, 0, 0);
    }

    #pragma unroll
    for (int im = 0; im < 4; ++im) {
        #pragma unroll
        for (int jn = 0; jn < 4; ++jn) {
            const int c = c0 + wc * 64 + jn * 16 + col;
            const float bv = bias[c];
            #pragma unroll
            for (int r = 0; r < 4; ++r) {
                const int m = m0 + wr * 64 + im * 16 + quad * 4 + r;
                out[(size_t)m * DMODEL + c] = acc[im][jn][r] + bv;
            }
        }
    }
}

extern "C" void kernel_launch(void* const* d_in, const int* in_sizes, int n_in,
                              void* d_out, int out_size, void* d_ws, size_t ws_size,
                              hipStream_t stream) {
    const float* x       = (const float*)d_in[0];
    const float* coords  = (const float*)d_in[1];
    const float* elev    = (const float*)d_in[2];
    const float* qkv_w   = (const float*)d_in[3];
    const float* qkv_b   = (const float*)d_in[4];
    const float* proj_w  = (const float*)d_in[5];
    const float* proj_b  = (const float*)d_in[6];
    const float* btable  = (const float*)d_in[7];
    const float* alpha   = (const float*)d_in[8];
    float* out = (float*)d_out;

    ushort_t* wsu = (ushort_t*)d_ws;
    ushort_t* xb  = wsu;
    ushort_t* wqb = wsu + 3145728;
    ushort_t* pwb = wsu + 4915200;
    ushort_t* Qb  = wsu + 5505024;
    ushort_t* Kb  = wsu + 8650752;
    ushort_t* Vtb = wsu + 11796480;
    ushort_t* Ob  = wsu + 14942208;
    unsigned* pck = (unsigned*)(wsu + 18087936);   // 4M uint32 = 16 MB

    convert_kernel<<<2688, 256, 0, stream>>>(x, qkv_w, proj_w, wsu);
    bias_pre<<<4096, 256, 0, stream>>>(coords, elev, alpha, pck);
    qkv_gemm<<<dim3(18, 32), 256, 0, stream>>>(xb, wqb, qkv_b, Qb, Kb, Vtb);
    attn_mfma<<<768, 256, 0, stream>>>(Qb, Kb, Vtb, pck, btable, Ob);
    proj_gemm<<<dim3(6, 32), 256, 0, stream>>>(Ob, pwb, proj_b, out);
}